// Round 1
// baseline (31.469 us; speedup 1.0000x reference)
//
#include <hip/hip_runtime.h>

#define IHH 306
#define KW 7
#define OUTC 10
#define FH 300
#define NPIX (FH * FH)            // 90000
#define KK (KW * KW)              // 49
#define BLK 256
#define NBLK_A ((NPIX + BLK - 1) / BLK)   // 352
#define NACC (2 * OUTC)           // 20
#define OUT_TOTAL 1890000
#define POOLED_END 90000
#define HIT_END 990000

__global__ __launch_bounds__(BLK) void compute_partials(
    const float* __restrict__ x,
    const float* __restrict__ kh,
    const float* __restrict__ km,
    float* __restrict__ partials)   // [NBLK_A][NACC]
{
    __shared__ float s_kh[OUTC * KK];
    __shared__ float s_km[OUTC * KK];
    for (int t = threadIdx.x; t < OUTC * KK; t += BLK) {
        s_kh[t] = kh[t];
        s_km[t] = km[t];
    }
    __syncthreads();

    float acc_h[OUTC];
    float acc_m[OUTC];
#pragma unroll
    for (int o = 0; o < OUTC; ++o) { acc_h[o] = 0.0f; acc_m[o] = 0.0f; }

    const int p = blockIdx.x * BLK + threadIdx.x;
    if (p < NPIX) {
        const int i = p / FH;
        const int j = p - i * FH;
        const float* xr = x + i * IHH + j;
        for (int u = 0; u < KW; ++u) {
#pragma unroll
            for (int v = 0; v < KW; ++v) {
                const float xv = xr[u * IHH + v];
                const int uv = u * KW + v;
#pragma unroll
                for (int o = 0; o < OUTC; ++o) {
                    const float dh = xv - s_kh[o * KK + uv];
                    const float dm = xv - s_km[o * KK + uv];
                    acc_h[o] += fminf(dh, 0.0f);
                    acc_m[o] += fmaxf(dm, 0.0f);
                }
            }
        }
    }

    // Block reduction: wave shuffle then cross-wave via LDS.
    const int lane = threadIdx.x & 63;
    const int wave = threadIdx.x >> 6;
    __shared__ float s_red[BLK / 64][NACC];
#pragma unroll
    for (int o = 0; o < OUTC; ++o) {
        float h = acc_h[o];
        float m = acc_m[o];
#pragma unroll
        for (int s = 32; s > 0; s >>= 1) {
            h += __shfl_xor(h, s);
            m += __shfl_xor(m, s);
        }
        if (lane == 0) {
            s_red[wave][o] = h;
            s_red[wave][OUTC + o] = m;
        }
    }
    __syncthreads();
    if (threadIdx.x < NACC) {
        float s = s_red[0][threadIdx.x] + s_red[1][threadIdx.x]
                + s_red[2][threadIdx.x] + s_red[3][threadIdx.x];
        partials[blockIdx.x * NACC + threadIdx.x] = s;
    }
}

__global__ void reduce_finals(const float* __restrict__ partials,
                              float* __restrict__ finals)
{
    const int a = threadIdx.x;
    if (a < NACC) {
        float s = 0.0f;
        for (int b = 0; b < NBLK_A; ++b) s += partials[b * NACC + a];
        finals[a] = s;
    }
}

__global__ __launch_bounds__(BLK) void fill_out(
    const float* __restrict__ finals,
    float4* __restrict__ out)
{
    const int idx4 = blockIdx.x * BLK + threadIdx.x;
    if (idx4 >= OUT_TOTAL / 4) return;
    const int base = idx4 * 4;
    float val;
    if (base < POOLED_END) {
        const int o = base / 9000;                    // pooled: 10 ch x 9000
        val = finals[o] - finals[OUTC + o];
    } else if (base < HIT_END) {
        const int o = (base - POOLED_END) / 90000;    // F_hit: 10 ch x 90000
        val = finals[o];
    } else {
        const int o = (base - HIT_END) / 90000;       // F_miss: 10 ch x 90000
        val = finals[OUTC + o];
    }
    out[idx4] = make_float4(val, val, val, val);
}

extern "C" void kernel_launch(void* const* d_in, const int* in_sizes, int n_in,
                              void* d_out, int out_size, void* d_ws, size_t ws_size,
                              hipStream_t stream) {
    const float* x  = (const float*)d_in[0];
    const float* kh = (const float*)d_in[1];
    const float* km = (const float*)d_in[2];
    float* out = (float*)d_out;

    float* partials = (float*)d_ws;                 // NBLK_A * NACC floats
    float* finals   = partials + NBLK_A * NACC;     // NACC floats

    compute_partials<<<NBLK_A, BLK, 0, stream>>>(x, kh, km, partials);
    reduce_finals<<<1, 64, 0, stream>>>(partials, finals);

    const int n4 = OUT_TOTAL / 4;                   // 472500
    fill_out<<<(n4 + BLK - 1) / BLK, BLK, 0, stream>>>(finals, (float4*)out);
}

// Round 2
// 30.857 us; speedup vs baseline: 1.0198x; 1.0198x over previous
//
#include <hip/hip_runtime.h>

#define IHH 306
#define KW 7
#define OUTC 10
#define FH 300
#define NPIX (FH * FH)            // 90000
#define KK (KW * KW)              // 49
#define BLK 256
#define NBA ((NPIX + BLK - 1) / BLK)   // 352 blocks in K1
#define NROWS 21                  // 10 hit-abs, 10 miss-abs, 1 x-sum
#define OUT_TOTAL 1890000
#define POOLED_END 90000
#define HIT_END 990000

// ws layout: partials[NROWS][NBA] floats, then ksums[20] floats.

__global__ __launch_bounds__(BLK) void k_partials(
    const float* __restrict__ x,
    const float* __restrict__ kh,
    const float* __restrict__ km,
    float* __restrict__ partials,   // [NROWS][NBA]
    float* __restrict__ ksums)      // [20]
{
    __shared__ float2 s_k[KK * OUTC];   // [tap][o] = (kh, km)
    for (int t = threadIdx.x; t < KK * OUTC; t += BLK) {
        const int tap = t / OUTC;
        const int o = t - tap * OUTC;
        s_k[t] = make_float2(kh[o * KK + tap], km[o * KK + tap]);
    }
    __syncthreads();

    float ah[OUTC], am[OUTC];
    float sx = 0.0f;
#pragma unroll
    for (int o = 0; o < OUTC; ++o) { ah[o] = 0.0f; am[o] = 0.0f; }

    const int p = blockIdx.x * BLK + threadIdx.x;
    if (p < NPIX) {
        const int i = p / FH;
        const int j = p - i * FH;
        const float* xr = x + i * IHH + j;
        for (int u = 0; u < KW; ++u) {
            for (int v = 0; v < KW; ++v) {
                const float xv = xr[u * IHH + v];
                sx += xv;
                const float2* wk = &s_k[(u * KW + v) * OUTC];
#pragma unroll
                for (int o = 0; o < OUTC; ++o) {
                    const float2 w = wk[o];
                    ah[o] += fabsf(xv - w.x);   // abs folds to src modifier
                    am[o] += fabsf(xv - w.y);
                }
            }
        }
    }

    // Wave shuffle reduce then cross-wave via LDS.
    const int lane = threadIdx.x & 63;
    const int wave = threadIdx.x >> 6;
    __shared__ float s_red[BLK / 64][NROWS];

    float vals[NROWS];
#pragma unroll
    for (int o = 0; o < OUTC; ++o) { vals[o] = ah[o]; vals[OUTC + o] = am[o]; }
    vals[2 * OUTC] = sx;

#pragma unroll
    for (int r = 0; r < NROWS; ++r) {
        float v = vals[r];
#pragma unroll
        for (int s = 32; s > 0; s >>= 1) v += __shfl_xor(v, s);
        if (lane == 0) s_red[wave][r] = v;
    }
    __syncthreads();
    if (threadIdx.x < NROWS) {
        const float s = s_red[0][threadIdx.x] + s_red[1][threadIdx.x]
                      + s_red[2][threadIdx.x] + s_red[3][threadIdx.x];
        partials[threadIdx.x * NBA + blockIdx.x] = s;
    }

    // Kernel-weight sums (linear term), once, by block 0.
    if (blockIdx.x == 0 && threadIdx.x < 2 * OUTC) {
        const float* kp = (threadIdx.x < OUTC)
            ? (kh + threadIdx.x * KK)
            : (km + (threadIdx.x - OUTC) * KK);
        float s = 0.0f;
        for (int t = 0; t < KK; ++t) s += kp[t];
        ksums[threadIdx.x] = s;
    }
}

__global__ __launch_bounds__(BLK) void k_fill(
    const float* __restrict__ partials,
    const float* __restrict__ ksums,
    float4* __restrict__ out)
{
    __shared__ float s_part[NROWS][8];
    __shared__ float s_o[3][OUTC];
    const int t = threadIdx.x;

    // Redundant per-block reduce of the 21x352 partial table (L2-hot).
    if (t < NROWS * 8) {
        const int r = t >> 3;
        const int s = t & 7;
        const float* row = partials + r * NBA;
        float acc = 0.0f;
        for (int c = s; c < NBA; c += 8) acc += row[c];
        s_part[r][s] = acc;
    }
    __syncthreads();
    if (t < NROWS) {
        float f = 0.0f;
#pragma unroll
        for (int s = 0; s < 8; ++s) f += s_part[t][s];
        s_part[t][0] = f;           // row t final
    }
    __syncthreads();
    if (t < OUTC) {
        const float Sx = s_part[2 * OUTC][0];
        const float Ah = s_part[t][0];
        const float Am = s_part[OUTC + t][0];
        const float Fh = 0.5f * ((Sx - (float)NPIX * ksums[t]) - Ah);
        const float Fm = 0.5f * ((Sx - (float)NPIX * ksums[OUTC + t]) + Am);
        s_o[0][t] = Fh - Fm;        // pooled value
        s_o[1][t] = Fh;             // F_hit_list value
        s_o[2][t] = Fm;             // F_miss_list value
    }
    __syncthreads();

    const int idx4 = blockIdx.x * BLK + t;
    if (idx4 >= OUT_TOTAL / 4) return;
    const int base = idx4 * 4;
    float val;
    if (base < POOLED_END) {
        val = s_o[0][base / 9000];                    // pooled: 10 ch x 9000
    } else if (base < HIT_END) {
        val = s_o[1][(base - POOLED_END) / 90000];    // F_hit: 10 ch x 90000
    } else {
        val = s_o[2][(base - HIT_END) / 90000];       // F_miss: 10 ch x 90000
    }
    out[idx4] = make_float4(val, val, val, val);
}

extern "C" void kernel_launch(void* const* d_in, const int* in_sizes, int n_in,
                              void* d_out, int out_size, void* d_ws, size_t ws_size,
                              hipStream_t stream) {
    const float* x  = (const float*)d_in[0];
    const float* kh = (const float*)d_in[1];
    const float* km = (const float*)d_in[2];
    float* out = (float*)d_out;

    float* partials = (float*)d_ws;                 // NROWS * NBA floats
    float* ksums    = partials + NROWS * NBA;       // 20 floats

    k_partials<<<NBA, BLK, 0, stream>>>(x, kh, km, partials, ksums);

    const int n4 = OUT_TOTAL / 4;                   // 472500
    k_fill<<<(n4 + BLK - 1) / BLK, BLK, 0, stream>>>(partials, ksums, (float4*)out);
}